// Round 5
// baseline (229.872 us; speedup 1.0000x reference)
//
#include <hip/hip_runtime.h>
#include <math.h>

#define S_LEN 2048
#define EMB   1024
#define NHEAD 8
#define DH    128
#define E3    3072
#define BM    32
#define NSPLIT 3
#define QSTRIDE  136   // Q/K LDS row stride (elems): 272B rows, b128-aligned
#define VTSTRIDE 40    // V^T LDS row stride: 80B rows, b128-aligned, 2-way banks
#define PTSTRIDE 40    // P LDS row stride: 80B rows, b128-aligned

typedef __bf16 bf16x8 __attribute__((ext_vector_type(8)));
typedef __bf16 bf16x4 __attribute__((ext_vector_type(4)));
typedef float  f32x4  __attribute__((ext_vector_type(4)));

// ---------------------------------------------------------------------------
// Kernel 1: fused gates + q/k hi-lo bf16 conversion. 8 rows per block
// (weights L2-reused x8), 32 threads per row.
// ---------------------------------------------------------------------------
__global__ __launch_bounds__(256) void gates_cvt_kernel(
    const float* __restrict__ q, const float* __restrict__ k,
    const float* __restrict__ v,
    const float* __restrict__ Wi, const float* __restrict__ bi,
    const float* __restrict__ Wf, const float* __restrict__ bf,
    __bf16* __restrict__ Qh, __bf16* __restrict__ Ql,
    __bf16* __restrict__ Kh, __bf16* __restrict__ Kl,
    float* __restrict__ ig, float* __restrict__ lf)
{
    const int tid = threadIdx.x;
    const int r = tid >> 5, ln = tid & 31;
    const int t = blockIdx.x * 8 + r;
    const float4* q4 = (const float4*)q + (size_t)t * 256;
    const float4* k4 = (const float4*)k + (size_t)t * 256;
    const float4* v4 = (const float4*)v + (size_t)t * 256;

    float4 qv[8], kv[8], vv[8];
    #pragma unroll
    for (int j = 0; j < 8; ++j) {
        qv[j] = q4[ln + j * 32];
        kv[j] = k4[ln + j * 32];
        vv[j] = v4[ln + j * 32];
    }
    // hi/lo bf16 split stores for q, k
    #pragma unroll
    for (int j = 0; j < 8; ++j) {
        size_t idx = (size_t)t * 256 + ln + j * 32;
        bf16x4 hi, lo;
        hi[0]=(__bf16)qv[j].x; hi[1]=(__bf16)qv[j].y; hi[2]=(__bf16)qv[j].z; hi[3]=(__bf16)qv[j].w;
        lo[0]=(__bf16)(qv[j].x-(float)hi[0]); lo[1]=(__bf16)(qv[j].y-(float)hi[1]);
        lo[2]=(__bf16)(qv[j].z-(float)hi[2]); lo[3]=(__bf16)(qv[j].w-(float)hi[3]);
        ((bf16x4*)Qh)[idx] = hi; ((bf16x4*)Ql)[idx] = lo;
        hi[0]=(__bf16)kv[j].x; hi[1]=(__bf16)kv[j].y; hi[2]=(__bf16)kv[j].z; hi[3]=(__bf16)kv[j].w;
        lo[0]=(__bf16)(kv[j].x-(float)hi[0]); lo[1]=(__bf16)(kv[j].y-(float)hi[1]);
        lo[2]=(__bf16)(kv[j].z-(float)hi[2]); lo[3]=(__bf16)(kv[j].w-(float)hi[3]);
        ((bf16x4*)Kh)[idx] = hi; ((bf16x4*)Kl)[idx] = lo;
    }
    // gate dots: 16 outputs (8 ig + 8 fg)
    float acc[16];
    #pragma unroll
    for (int g = 0; g < 16; ++g) {
        const float* wrow = (g < 8) ? (Wi + g * E3) : (Wf + (g - 8) * E3);
        const float4* w4 = (const float4*)wrow;
        float s = 0.f;
        #pragma unroll
        for (int j = 0; j < 8; ++j) {
            float4 a = w4[ln + j * 32];
            float4 b = w4[256 + ln + j * 32];
            float4 c = w4[512 + ln + j * 32];
            s += a.x*qv[j].x + a.y*qv[j].y + a.z*qv[j].z + a.w*qv[j].w
               + b.x*kv[j].x + b.y*kv[j].y + b.z*kv[j].z + b.w*kv[j].w
               + c.x*vv[j].x + c.y*vv[j].y + c.z*vv[j].z + c.w*vv[j].w;
        }
        acc[g] = s;
    }
    #pragma unroll
    for (int g = 0; g < 16; ++g)
        for (int o = 16; o > 0; o >>= 1) acc[g] += __shfl_down(acc[g], o, 32);
    if (ln == 0) {
        #pragma unroll
        for (int g = 0; g < 8; ++g) ig[g * S_LEN + t] = acc[g] + bi[g];
        #pragma unroll
        for (int g = 0; g < 8; ++g) {
            float x = acc[8 + g] + bf[g];
            lf[g * S_LEN + t] = fminf(x, 0.f) - log1pf(expf(-fabsf(x)));
        }
    }
}

// ---------------------------------------------------------------------------
// Kernel 2: v fp32 [S][EMB] -> bf16 V^T [EMB][S]. 32x32 LDS transpose.
// ---------------------------------------------------------------------------
__global__ __launch_bounds__(256) void transpose_v_kernel(
    const float* __restrict__ v, __bf16* __restrict__ Vt)
{
    __shared__ __bf16 tile[32][33];
    const int sb = blockIdx.x * 32, eb = blockIdx.y * 32;
    #pragma unroll
    for (int i = 0; i < 4; ++i) {
        int lin = threadIdx.x + i * 256;
        int sr = lin >> 5, ec = lin & 31;
        tile[ec][sr] = (__bf16)v[(size_t)(sb + sr) * EMB + eb + ec];
    }
    __syncthreads();
    #pragma unroll
    for (int i = 0; i < 4; ++i) {
        int lin = threadIdx.x + i * 256;
        int er = lin >> 5, sc = lin & 31;
        Vt[(size_t)(eb + er) * S_LEN + sb + sc] = tile[er][sc];
    }
}

// ---------------------------------------------------------------------------
// Kernel 3: cumsum of lf -> F, plus gate-max precompute:
//   u[t] = ig[t] - F[t+1];  upmax = within-32-block prefix max of u;
//   umax[j] = per-32-block max.  (Rank-1 structure: rowmax = Fq[s] + umax.)
// ---------------------------------------------------------------------------
__global__ __launch_bounds__(256) void cumsum_aux_kernel(
    const float* __restrict__ lf, const float* __restrict__ ig,
    float* __restrict__ F, float* __restrict__ ug,
    float* __restrict__ umax, float* __restrict__ upmax)
{
    const int h = blockIdx.x, tid = threadIdx.x;
    __shared__ float ssum[256];
    float loc[8];
    const int base = tid * 8;
    float s = 0.f;
    for (int i = 0; i < 8; i++) { s += lf[h * S_LEN + base + i]; loc[i] = s; }
    ssum[tid] = s;
    __syncthreads();
    for (int o = 1; o < 256; o <<= 1) {
        float add = (tid >= o) ? ssum[tid - o] : 0.f;
        __syncthreads();
        ssum[tid] += add;
        __syncthreads();
    }
    float prev = (tid > 0) ? ssum[tid - 1] : 0.f;
    float* Fh = F + h * (S_LEN + 1);
    if (tid == 0) Fh[0] = 0.f;
    for (int i = 0; i < 8; i++) Fh[base + i + 1] = prev + loc[i];
    __syncthreads();
    if (tid < 64) {
        float run = -INFINITY;
        const int b0 = tid * 32;
        for (int i = 0; i < 32; ++i) {
            int t = b0 + i;
            float u = ig[h * S_LEN + t] - Fh[t + 1];
            run = fmaxf(run, u);
            ug[h * S_LEN + t] = u;
            upmax[h * S_LEN + t] = run;
        }
        umax[h * 64 + tid] = run;
    }
}

// ---------------------------------------------------------------------------
// Kernel 4: flash mLSTM. Split-bf16 QK^T, split-K x3, precomputed gate
// maxima (no in-kernel max reduction), 3 barriers/tile, b128 staging with
// register prefetch. Flat grid 768, XCD swizzle: head = blockid & 7.
// ---------------------------------------------------------------------------
__global__ __launch_bounds__(256, 3) void mlstm_mfma(
    const __bf16* __restrict__ Qhg, const __bf16* __restrict__ Qlg,
    const __bf16* __restrict__ Khg, const __bf16* __restrict__ Klg,
    const __bf16* __restrict__ Vtg,
    const float* __restrict__ ug, const float* __restrict__ umaxg,
    const float* __restrict__ upmaxg, const float* __restrict__ F,
    float* __restrict__ Opart, float* __restrict__ msplit,
    float* __restrict__ lsplit)
{
    const int flat = blockIdx.x;
    const int h = flat & 7;
    const int rest = flat >> 3;
    const int xx = rest & 31, z = rest >> 5;
    const int tid  = threadIdx.x;
    const int lane = tid & 63, w = tid >> 6;
    const int quad = lane >> 4, l15 = lane & 15;
    const int mi = w & 1, ni = w >> 1;

    __shared__ __bf16 Qh[BM * QSTRIDE], Ql[BM * QSTRIDE];
    __shared__ __bf16 Kh[BM * QSTRIDE], Kl[BM * QSTRIDE];
    __shared__ __bf16 Vt[DH * VTSTRIDE];
    __shared__ __bf16 Pt[BM * PTSTRIDE];
    __shared__ float tsum[2][BM];

    const float* Fh = F + h * (S_LEN + 1);
    const float* ugh = ug + h * S_LEN;
    const float scale = 0.088388347648318447f; // 1/sqrt(128)
    const int kr  = tid >> 4, kc8 = tid & 15;  // Q/K staging (b128)
    const int vr0 = tid >> 2, vc0 = tid & 3;   // Vt staging (b128)

    for (int pair = 0; pair < 2; ++pair) {
        const int qt = (pair == 0) ? xx : 63 - xx;
        const int qb = qt * BM;
        const int nj = qt + 1;
        const int j0 = (z * nj) / NSPLIT, j1 = ((z + 1) * nj) / NSPLIT;

        __syncthreads(); // S0: previous pair's LDS consumers done
        #pragma unroll
        for (int i = 0; i < 2; ++i) {
            int row = kr + 16 * i;
            size_t g = (size_t)(qb + row) * EMB + h * DH + kc8 * 8;
            *(bf16x8*)&Qh[row * QSTRIDE + kc8 * 8] = *(const bf16x8*)(Qhg + g);
            *(bf16x8*)&Ql[row * QSTRIDE + kc8 * 8] = *(const bf16x8*)(Qlg + g);
        }
        float fq[4], dm[4];
        #pragma unroll
        for (int r = 0; r < 4; ++r) {
            int ri = mi * 16 + quad * 4 + r;
            fq[r] = Fh[qb + ri + 1];
            dm[r] = upmaxg[h * S_LEN + qb + ri];   // diag-tile row max offset
        }
        float m_r[4] = {-INFINITY, -INFINITY, -INFINITY, -INFINITY};
        float l_r[4] = {0.f, 0.f, 0.f, 0.f};
        f32x4 Oacc[4] = {{0,0,0,0},{0,0,0,0},{0,0,0,0},{0,0,0,0}};

        bf16x8 pk[2], pl[2], pv[2];
        if (j0 < j1) {
            const int tb = j0 * BM;
            #pragma unroll
            for (int i = 0; i < 2; ++i) {
                int row = kr + 16 * i;
                size_t g = (size_t)(tb + row) * EMB + h * DH + kc8 * 8;
                pk[i] = *(const bf16x8*)(Khg + g);
                pl[i] = *(const bf16x8*)(Klg + g);
                pv[i] = *(const bf16x8*)(Vtg + (size_t)(h * DH + vr0 + 64 * i) * S_LEN + tb + vc0 * 8);
            }
        }

        for (int j = j0; j < j1; ++j) {
            const int tb = j * BM;
            const bool diag = (j == qt);
            __syncthreads(); // A: prev-iter LDS consumers done
            #pragma unroll
            for (int i = 0; i < 2; ++i) {
                int row = kr + 16 * i;
                *(bf16x8*)&Kh[row * QSTRIDE + kc8 * 8] = pk[i];
                *(bf16x8*)&Kl[row * QSTRIDE + kc8 * 8] = pl[i];
                *(bf16x8*)&Vt[(vr0 + 64 * i) * VTSTRIDE + vc0 * 8] = pv[i];
            }
            __syncthreads(); // B: tiles staged
            if (j + 1 < j1) {  // prefetch next tile
                const int tb2 = tb + BM;
                #pragma unroll
                for (int i = 0; i < 2; ++i) {
                    int row = kr + 16 * i;
                    size_t g = (size_t)(tb2 + row) * EMB + h * DH + kc8 * 8;
                    pk[i] = *(const bf16x8*)(Khg + g);
                    pl[i] = *(const bf16x8*)(Klg + g);
                    pv[i] = *(const bf16x8*)(Vtg + (size_t)(h * DH + vr0 + 64 * i) * S_LEN + tb2 + vc0 * 8);
                }
            }
            // ---- S = Q K^T (split-bf16: Qh*Kh + Qh*Kl + Ql*Kh) ----
            f32x4 Sacc = {0, 0, 0, 0};
            #pragma unroll
            for (int kk = 0; kk < 4; ++kk) {
                const int ao = (mi * 16 + l15) * QSTRIDE + kk * 32 + quad * 8;
                const int bo = (ni * 16 + l15) * QSTRIDE + kk * 32 + quad * 8;
                bf16x8 ah = *(const bf16x8*)&Qh[ao];
                bf16x8 al = *(const bf16x8*)&Ql[ao];
                bf16x8 bh = *(const bf16x8*)&Kh[bo];
                bf16x8 bl = *(const bf16x8*)&Kl[bo];
                Sacc = __builtin_amdgcn_mfma_f32_16x16x32_bf16(ah, bh, Sacc, 0, 0, 0);
                Sacc = __builtin_amdgcn_mfma_f32_16x16x32_bf16(ah, bl, Sacc, 0, 0, 0);
                Sacc = __builtin_amdgcn_mfma_f32_16x16x32_bf16(al, bh, Sacc, 0, 0, 0);
            }
            // ---- gates: m/alpha pure register math (precomputed maxima) ----
            const int tc = ni * 16 + l15;
            const float ut = ugh[tb + tc];
            const float umj = umaxg[h * 64 + j];
            #pragma unroll
            for (int r = 0; r < 4; ++r) {
                int ri = mi * 16 + quad * 4 + r;
                float mt = fq[r] + (diag ? dm[r] : umj);
                float mn = fmaxf(m_r[r], mt);
                float alpha = __expf(m_r[r] - mn);  // first tile: exp(-inf)=0
                m_r[r] = mn;
                l_r[r] *= alpha;
                Oacc[0][r] *= alpha; Oacc[1][r] *= alpha;
                Oacc[2][r] *= alpha; Oacc[3][r] *= alpha;
                float p = __expf(fq[r] + ut - mn) * Sacc[r] * scale;
                if (diag && (tc > ri)) p = 0.f;     // causal mask (diag tile only)
                float x = p;
                #pragma unroll
                for (int o = 1; o < 16; o <<= 1) x += __shfl_xor(x, o);
                if (l15 == 0) tsum[ni][ri] = x;
                Pt[ri * PTSTRIDE + tc] = (__bf16)p;
            }
            __syncthreads(); // D: tsum + Pt visible
            #pragma unroll
            for (int r = 0; r < 4; ++r) {
                int ri = mi * 16 + quad * 4 + r;
                l_r[r] += tsum[0][ri] + tsum[1][ri];
            }
            // ---- O += P V ----
            bf16x8 pa = *(const bf16x8*)&Pt[(mi * 16 + l15) * PTSTRIDE + quad * 8];
            #pragma unroll
            for (int nt = 0; nt < 4; ++nt) {
                int n = ni * 64 + nt * 16 + l15;
                bf16x4 lo = *(const bf16x4*)&Vt[n * VTSTRIDE + quad * 8];
                bf16x4 hi = *(const bf16x4*)&Vt[n * VTSTRIDE + quad * 8 + 4];
                bf16x8 b;
                b[0] = lo[0]; b[1] = lo[1]; b[2] = lo[2]; b[3] = lo[3];
                b[4] = hi[0]; b[5] = hi[1]; b[6] = hi[2]; b[7] = hi[3];
                Oacc[nt] = __builtin_amdgcn_mfma_f32_16x16x32_bf16(pa, b, Oacc[nt], 0, 0, 0);
            }
        }
        // ---- epilogue: unnormalized partials ----
        float* Oz = Opart + (size_t)z * S_LEN * EMB;
        #pragma unroll
        for (int nt = 0; nt < 4; ++nt) {
            #pragma unroll
            for (int r = 0; r < 4; ++r) {
                int ri = mi * 16 + quad * 4 + r;
                Oz[(size_t)(qb + ri) * EMB + h * DH + ni * 64 + nt * 16 + l15] = Oacc[nt][r];
            }
        }
        if (ni == 0 && l15 == 0) {
            #pragma unroll
            for (int r = 0; r < 4; ++r) {
                int ri = mi * 16 + quad * 4 + r;
                msplit[(z * NHEAD + h) * S_LEN + qb + ri] = m_r[r];
                lsplit[(z * NHEAD + h) * S_LEN + qb + ri] = l_r[r];
            }
        }
    }
}

// ---------------------------------------------------------------------------
// Kernel 5: combine split-K partials + normalize + residual LayerNorm.
// ---------------------------------------------------------------------------
__global__ __launch_bounds__(256) void combine_ln_kernel(
    const float* __restrict__ Opart, const float* __restrict__ msplit,
    const float* __restrict__ lsplit, const float* __restrict__ lnw,
    float* __restrict__ out)
{
    const int s = blockIdx.x, tid = threadIdx.x;
    __shared__ float es_s[NSPLIT][NHEAD];
    __shared__ float rn_s[NHEAD];
    __shared__ float red[4];
    if (tid < NHEAD) {
        float m0 = msplit[(0 * NHEAD + tid) * S_LEN + s];
        float m1 = msplit[(1 * NHEAD + tid) * S_LEN + s];
        float m2 = msplit[(2 * NHEAD + tid) * S_LEN + s];
        float m = fmaxf(m0, fmaxf(m1, m2));
        float e0 = __expf(m0 - m), e1 = __expf(m1 - m), e2 = __expf(m2 - m);
        float l = e0 * lsplit[(0 * NHEAD + tid) * S_LEN + s]
                + e1 * lsplit[(1 * NHEAD + tid) * S_LEN + s]
                + e2 * lsplit[(2 * NHEAD + tid) * S_LEN + s];
        es_s[0][tid] = e0; es_s[1][tid] = e1; es_s[2][tid] = e2;
        rn_s[tid] = 1.f / (fmaxf(fabsf(l), __expf(-m)) + 1e-6f);
    }
    __syncthreads();
    const size_t SE = (size_t)S_LEN * EMB;
    float x[4];
    float sum = 0.f;
    #pragma unroll
    for (int i = 0; i < 4; i++) {
        int col = tid + i * 256;
        int hh = col >> 7;
        size_t off = (size_t)s * EMB + col;
        float val = es_s[0][hh] * Opart[off]
                  + es_s[1][hh] * Opart[SE + off]
                  + es_s[2][hh] * Opart[2 * SE + off];
        x[i] = val * rn_s[hh];
        sum += x[i];
    }
    for (int o = 32; o > 0; o >>= 1) sum += __shfl_down(sum, o, 64);
    if ((tid & 63) == 0) red[tid >> 6] = sum;
    __syncthreads();
    sum = red[0] + red[1] + red[2] + red[3];
    const float mu = sum * (1.f / EMB);
    float vs = 0.f;
    #pragma unroll
    for (int i = 0; i < 4; i++) { float d = x[i] - mu; vs += d * d; }
    __syncthreads();
    for (int o = 32; o > 0; o >>= 1) vs += __shfl_down(vs, o, 64);
    if ((tid & 63) == 0) red[tid >> 6] = vs;
    __syncthreads();
    vs = red[0] + red[1] + red[2] + red[3];
    const float rstd = rsqrtf(vs * (1.f / EMB) + 1e-5f);
    #pragma unroll
    for (int i = 0; i < 4; i++) {
        int c = tid + i * 256;
        out[(size_t)s * EMB + c] = (x[i] - mu) * rstd * (1.f + lnw[c]);
    }
}

// ---------------------------------------------------------------------------
extern "C" void kernel_launch(void* const* d_in, const int* in_sizes, int n_in,
                              void* d_out, int out_size, void* d_ws, size_t ws_size,
                              hipStream_t stream)
{
    const float* q   = (const float*)d_in[0];
    const float* k   = (const float*)d_in[1];
    const float* v   = (const float*)d_in[2];
    const float* Wi  = (const float*)d_in[3];
    const float* bi  = (const float*)d_in[4];
    const float* Wf  = (const float*)d_in[5];
    const float* bf  = (const float*)d_in[6];
    const float* lnw = (const float*)d_in[7];
    float* out = (float*)d_out;

    // workspace layout (floats first, then bf16 arrays, then big fp32):
    float* ws = (float*)d_ws;
    float* ig    = ws;                          // NH*S
    float* lf    = ig + NHEAD * S_LEN;          // NH*S
    float* F     = lf + NHEAD * S_LEN;          // NH*(S+1)
    float* ugw   = F + NHEAD * (S_LEN + 1);     // NH*S
    float* umaxw = ugw + NHEAD * S_LEN;         // NH*64
    float* upmaxw= umaxw + NHEAD * 64;          // NH*S
    __bf16* Qh = (__bf16*)(upmaxw + NHEAD * S_LEN);
    const size_t SEb = (size_t)S_LEN * EMB;
    __bf16* Ql  = Qh + SEb;
    __bf16* Kh  = Ql + SEb;
    __bf16* Kl  = Kh + SEb;
    __bf16* Vtg = Kl + SEb;
    float* Opart  = (float*)(Vtg + SEb);        // 3*S*EMB
    float* msplit = Opart + (size_t)NSPLIT * S_LEN * EMB;
    float* lsplit = msplit + NSPLIT * NHEAD * S_LEN;

    gates_cvt_kernel<<<S_LEN / 8, 256, 0, stream>>>(
        q, k, v, Wi, bi, Wf, bf, Qh, Ql, Kh, Kl, ig, lf);
    transpose_v_kernel<<<dim3(S_LEN / 32, EMB / 32), 256, 0, stream>>>(v, Vtg);
    cumsum_aux_kernel<<<NHEAD, 256, 0, stream>>>(lf, ig, F, ugw, umaxw, upmaxw);
    mlstm_mfma<<<32 * NHEAD * NSPLIT, 256, 0, stream>>>(
        Qh, Ql, Kh, Kl, Vtg, ugw, umaxw, upmaxw, F, Opart, msplit, lsplit);
    combine_ln_kernel<<<S_LEN, 256, 0, stream>>>(Opart, msplit, lsplit, lnw, out);
}

// Round 6
// 188.925 us; speedup vs baseline: 1.2167x; 1.2167x over previous
//
#include <hip/hip_runtime.h>
#include <math.h>

#define S_LEN 2048
#define EMB   1024
#define NHEAD 8
#define DH    128
#define E3    3072
#define BM    32
#define NSPLIT 3
#define QSTRIDE  136   // Q/K LDS row stride (elems): 272B rows, b128-aligned
#define VTSTRIDE 40    // V^T LDS row stride: 80B rows, b128-aligned, 2-way banks
#define PTSTRIDE 40    // P LDS row stride: 80B rows, b128-aligned

typedef __bf16 bf16x8 __attribute__((ext_vector_type(8)));
typedef __bf16 bf16x4 __attribute__((ext_vector_type(4)));
typedef float  f32x4  __attribute__((ext_vector_type(4)));

// ---------------------------------------------------------------------------
// Kernel 1: fused gates + q/k hi-lo bf16 cvt. One block per row t, 256 thr;
// thread owns 4 contiguous elems (12 input VGPRs -> no spill, unlike R5).
// Weights (196 KB) are L2-hot across the 2048 blocks.
// ---------------------------------------------------------------------------
__global__ __launch_bounds__(256) void gates_cvt_kernel(
    const float* __restrict__ q, const float* __restrict__ k,
    const float* __restrict__ v,
    const float* __restrict__ Wi, const float* __restrict__ bi,
    const float* __restrict__ Wf, const float* __restrict__ bf,
    __bf16* __restrict__ Qh, __bf16* __restrict__ Ql,
    __bf16* __restrict__ Kh, __bf16* __restrict__ Kl,
    float* __restrict__ ig, float* __restrict__ lf)
{
    const int t = blockIdx.x, tid = threadIdx.x;
    const float4 qv = ((const float4*)q)[(size_t)t * 256 + tid];
    const float4 kv = ((const float4*)k)[(size_t)t * 256 + tid];
    const float4 vv = ((const float4*)v)[(size_t)t * 256 + tid];

    // hi/lo bf16 split stores for q, k (coalesced b64)
    {
        size_t idx = (size_t)t * 256 + tid;
        bf16x4 hi, lo;
        hi[0]=(__bf16)qv.x; hi[1]=(__bf16)qv.y; hi[2]=(__bf16)qv.z; hi[3]=(__bf16)qv.w;
        lo[0]=(__bf16)(qv.x-(float)hi[0]); lo[1]=(__bf16)(qv.y-(float)hi[1]);
        lo[2]=(__bf16)(qv.z-(float)hi[2]); lo[3]=(__bf16)(qv.w-(float)hi[3]);
        ((bf16x4*)Qh)[idx] = hi; ((bf16x4*)Ql)[idx] = lo;
        hi[0]=(__bf16)kv.x; hi[1]=(__bf16)kv.y; hi[2]=(__bf16)kv.z; hi[3]=(__bf16)kv.w;
        lo[0]=(__bf16)(kv.x-(float)hi[0]); lo[1]=(__bf16)(kv.y-(float)hi[1]);
        lo[2]=(__bf16)(kv.z-(float)hi[2]); lo[3]=(__bf16)(kv.w-(float)hi[3]);
        ((bf16x4*)Kh)[idx] = hi; ((bf16x4*)Kl)[idx] = lo;
    }
    // 16 gate dots (8 ig + 8 fg); 3 coalesced weight float4 loads per gate
    float acc[16];
    #pragma unroll
    for (int g = 0; g < 16; ++g) {
        const float4* w4 = (const float4*)((g < 8) ? (Wi + g * E3) : (Wf + (g - 8) * E3));
        float4 a = w4[tid], b = w4[256 + tid], c = w4[512 + tid];
        acc[g] = a.x*qv.x + a.y*qv.y + a.z*qv.z + a.w*qv.w
               + b.x*kv.x + b.y*kv.y + b.z*kv.z + b.w*kv.w
               + c.x*vv.x + c.y*vv.y + c.z*vv.z + c.w*vv.w;
    }
    __shared__ float red[16][4];
    const int w = tid >> 6, lane = tid & 63;
    #pragma unroll
    for (int g = 0; g < 16; ++g) {
        float x = acc[g];
        for (int o = 32; o > 0; o >>= 1) x += __shfl_down(x, o, 64);
        if (lane == 0) red[g][w] = x;
    }
    __syncthreads();
    if (tid < 16) {
        float s = red[tid][0] + red[tid][1] + red[tid][2] + red[tid][3];
        if (tid < 8) {
            ig[tid * S_LEN + t] = s + bi[tid];
        } else {
            int h = tid - 8;
            float x = s + bf[h];
            lf[h * S_LEN + t] = fminf(x, 0.f) - log1pf(expf(-fabsf(x)));
        }
    }
}

// ---------------------------------------------------------------------------
// Kernel 2: v fp32 [S][EMB] -> bf16 V^T [EMB][S]. 32x32 LDS transpose.
// ---------------------------------------------------------------------------
__global__ __launch_bounds__(256) void transpose_v_kernel(
    const float* __restrict__ v, __bf16* __restrict__ Vt)
{
    __shared__ __bf16 tile[32][33];
    const int sb = blockIdx.x * 32, eb = blockIdx.y * 32;
    #pragma unroll
    for (int i = 0; i < 4; ++i) {
        int lin = threadIdx.x + i * 256;
        int sr = lin >> 5, ec = lin & 31;
        tile[ec][sr] = (__bf16)v[(size_t)(sb + sr) * EMB + eb + ec];
    }
    __syncthreads();
    #pragma unroll
    for (int i = 0; i < 4; ++i) {
        int lin = threadIdx.x + i * 256;
        int er = lin >> 5, sc = lin & 31;
        Vt[(size_t)(eb + er) * S_LEN + sb + sc] = tile[er][sc];
    }
}

// ---------------------------------------------------------------------------
// Kernel 3: cumsum of lf -> F, plus gate-max precompute:
//   u[t] = ig[t] - F[t+1];  upmax = within-32-block prefix max of u;
//   umax[j] = per-32-block max.  (Rank-1 structure: rowmax = Fq[s] + umax.)
// ---------------------------------------------------------------------------
__global__ __launch_bounds__(256) void cumsum_aux_kernel(
    const float* __restrict__ lf, const float* __restrict__ ig,
    float* __restrict__ F, float* __restrict__ ug,
    float* __restrict__ umax, float* __restrict__ upmax)
{
    const int h = blockIdx.x, tid = threadIdx.x;
    __shared__ float ssum[256];
    float loc[8];
    const int base = tid * 8;
    float s = 0.f;
    for (int i = 0; i < 8; i++) { s += lf[h * S_LEN + base + i]; loc[i] = s; }
    ssum[tid] = s;
    __syncthreads();
    for (int o = 1; o < 256; o <<= 1) {
        float add = (tid >= o) ? ssum[tid - o] : 0.f;
        __syncthreads();
        ssum[tid] += add;
        __syncthreads();
    }
    float prev = (tid > 0) ? ssum[tid - 1] : 0.f;
    float* Fh = F + h * (S_LEN + 1);
    if (tid == 0) Fh[0] = 0.f;
    for (int i = 0; i < 8; i++) Fh[base + i + 1] = prev + loc[i];
    __syncthreads();
    if (tid < 64) {
        float run = -INFINITY;
        const int b0 = tid * 32;
        for (int i = 0; i < 32; ++i) {
            int t = b0 + i;
            float u = ig[h * S_LEN + t] - Fh[t + 1];
            run = fmaxf(run, u);
            ug[h * S_LEN + t] = u;
            upmax[h * S_LEN + t] = run;
        }
        umax[h * 64 + tid] = run;
    }
}

// ---------------------------------------------------------------------------
// Kernel 4: flash mLSTM (unchanged from R5). Split-bf16 QK^T, split-K x3,
// precomputed gate maxima, 3 barriers/tile, b128 staging + reg prefetch.
// Flat grid 768, XCD swizzle: head = blockid & 7.
// ---------------------------------------------------------------------------
__global__ __launch_bounds__(256, 3) void mlstm_mfma(
    const __bf16* __restrict__ Qhg, const __bf16* __restrict__ Qlg,
    const __bf16* __restrict__ Khg, const __bf16* __restrict__ Klg,
    const __bf16* __restrict__ Vtg,
    const float* __restrict__ ug, const float* __restrict__ umaxg,
    const float* __restrict__ upmaxg, const float* __restrict__ F,
    float* __restrict__ Opart, float* __restrict__ msplit,
    float* __restrict__ lsplit)
{
    const int flat = blockIdx.x;
    const int h = flat & 7;
    const int rest = flat >> 3;
    const int xx = rest & 31, z = rest >> 5;
    const int tid  = threadIdx.x;
    const int lane = tid & 63, w = tid >> 6;
    const int quad = lane >> 4, l15 = lane & 15;
    const int mi = w & 1, ni = w >> 1;

    __shared__ __bf16 Qh[BM * QSTRIDE], Ql[BM * QSTRIDE];
    __shared__ __bf16 Kh[BM * QSTRIDE], Kl[BM * QSTRIDE];
    __shared__ __bf16 Vt[DH * VTSTRIDE];
    __shared__ __bf16 Pt[BM * PTSTRIDE];
    __shared__ float tsum[2][BM];

    const float* Fh = F + h * (S_LEN + 1);
    const float* ugh = ug + h * S_LEN;
    const float scale = 0.088388347648318447f; // 1/sqrt(128)
    const int kr  = tid >> 4, kc8 = tid & 15;  // Q/K staging (b128)
    const int vr0 = tid >> 2, vc0 = tid & 3;   // Vt staging (b128)

    for (int pair = 0; pair < 2; ++pair) {
        const int qt = (pair == 0) ? xx : 63 - xx;
        const int qb = qt * BM;
        const int nj = qt + 1;
        const int j0 = (z * nj) / NSPLIT, j1 = ((z + 1) * nj) / NSPLIT;

        __syncthreads(); // S0: previous pair's LDS consumers done
        #pragma unroll
        for (int i = 0; i < 2; ++i) {
            int row = kr + 16 * i;
            size_t g = (size_t)(qb + row) * EMB + h * DH + kc8 * 8;
            *(bf16x8*)&Qh[row * QSTRIDE + kc8 * 8] = *(const bf16x8*)(Qhg + g);
            *(bf16x8*)&Ql[row * QSTRIDE + kc8 * 8] = *(const bf16x8*)(Qlg + g);
        }
        float fq[4], dm[4];
        #pragma unroll
        for (int r = 0; r < 4; ++r) {
            int ri = mi * 16 + quad * 4 + r;
            fq[r] = Fh[qb + ri + 1];
            dm[r] = upmaxg[h * S_LEN + qb + ri];   // diag-tile row max offset
        }
        float m_r[4] = {-INFINITY, -INFINITY, -INFINITY, -INFINITY};
        float l_r[4] = {0.f, 0.f, 0.f, 0.f};
        f32x4 Oacc[4] = {{0,0,0,0},{0,0,0,0},{0,0,0,0},{0,0,0,0}};

        bf16x8 pk[2], pl[2], pv[2];
        if (j0 < j1) {
            const int tb = j0 * BM;
            #pragma unroll
            for (int i = 0; i < 2; ++i) {
                int row = kr + 16 * i;
                size_t g = (size_t)(tb + row) * EMB + h * DH + kc8 * 8;
                pk[i] = *(const bf16x8*)(Khg + g);
                pl[i] = *(const bf16x8*)(Klg + g);
                pv[i] = *(const bf16x8*)(Vtg + (size_t)(h * DH + vr0 + 64 * i) * S_LEN + tb + vc0 * 8);
            }
        }

        for (int j = j0; j < j1; ++j) {
            const int tb = j * BM;
            const bool diag = (j == qt);
            __syncthreads(); // A: prev-iter LDS consumers done
            #pragma unroll
            for (int i = 0; i < 2; ++i) {
                int row = kr + 16 * i;
                *(bf16x8*)&Kh[row * QSTRIDE + kc8 * 8] = pk[i];
                *(bf16x8*)&Kl[row * QSTRIDE + kc8 * 8] = pl[i];
                *(bf16x8*)&Vt[(vr0 + 64 * i) * VTSTRIDE + vc0 * 8] = pv[i];
            }
            __syncthreads(); // B: tiles staged
            if (j + 1 < j1) {  // prefetch next tile
                const int tb2 = tb + BM;
                #pragma unroll
                for (int i = 0; i < 2; ++i) {
                    int row = kr + 16 * i;
                    size_t g = (size_t)(tb2 + row) * EMB + h * DH + kc8 * 8;
                    pk[i] = *(const bf16x8*)(Khg + g);
                    pl[i] = *(const bf16x8*)(Klg + g);
                    pv[i] = *(const bf16x8*)(Vtg + (size_t)(h * DH + vr0 + 64 * i) * S_LEN + tb2 + vc0 * 8);
                }
            }
            // ---- S = Q K^T (split-bf16: Qh*Kh + Qh*Kl + Ql*Kh) ----
            f32x4 Sacc = {0, 0, 0, 0};
            #pragma unroll
            for (int kk = 0; kk < 4; ++kk) {
                const int ao = (mi * 16 + l15) * QSTRIDE + kk * 32 + quad * 8;
                const int bo = (ni * 16 + l15) * QSTRIDE + kk * 32 + quad * 8;
                bf16x8 ah = *(const bf16x8*)&Qh[ao];
                bf16x8 al = *(const bf16x8*)&Ql[ao];
                bf16x8 bh = *(const bf16x8*)&Kh[bo];
                bf16x8 bl = *(const bf16x8*)&Kl[bo];
                Sacc = __builtin_amdgcn_mfma_f32_16x16x32_bf16(ah, bh, Sacc, 0, 0, 0);
                Sacc = __builtin_amdgcn_mfma_f32_16x16x32_bf16(ah, bl, Sacc, 0, 0, 0);
                Sacc = __builtin_amdgcn_mfma_f32_16x16x32_bf16(al, bh, Sacc, 0, 0, 0);
            }
            // ---- gates: m/alpha pure register math (precomputed maxima) ----
            const int tc = ni * 16 + l15;
            const float ut = ugh[tb + tc];
            const float umj = umaxg[h * 64 + j];
            #pragma unroll
            for (int r = 0; r < 4; ++r) {
                int ri = mi * 16 + quad * 4 + r;
                float mt = fq[r] + (diag ? dm[r] : umj);
                float mn = fmaxf(m_r[r], mt);
                float alpha = __expf(m_r[r] - mn);  // first tile: exp(-inf)=0
                m_r[r] = mn;
                l_r[r] *= alpha;
                Oacc[0][r] *= alpha; Oacc[1][r] *= alpha;
                Oacc[2][r] *= alpha; Oacc[3][r] *= alpha;
                float p = __expf(fq[r] + ut - mn) * Sacc[r] * scale;
                if (diag && (tc > ri)) p = 0.f;     // causal mask (diag tile only)
                float x = p;
                #pragma unroll
                for (int o = 1; o < 16; o <<= 1) x += __shfl_xor(x, o);
                if (l15 == 0) tsum[ni][ri] = x;
                Pt[ri * PTSTRIDE + tc] = (__bf16)p;
            }
            __syncthreads(); // D: tsum + Pt visible
            #pragma unroll
            for (int r = 0; r < 4; ++r) {
                int ri = mi * 16 + quad * 4 + r;
                l_r[r] += tsum[0][ri] + tsum[1][ri];
            }
            // ---- O += P V ----
            bf16x8 pa = *(const bf16x8*)&Pt[(mi * 16 + l15) * PTSTRIDE + quad * 8];
            #pragma unroll
            for (int nt = 0; nt < 4; ++nt) {
                int n = ni * 64 + nt * 16 + l15;
                bf16x4 lo = *(const bf16x4*)&Vt[n * VTSTRIDE + quad * 8];
                bf16x4 hi = *(const bf16x4*)&Vt[n * VTSTRIDE + quad * 8 + 4];
                bf16x8 b;
                b[0] = lo[0]; b[1] = lo[1]; b[2] = lo[2]; b[3] = lo[3];
                b[4] = hi[0]; b[5] = hi[1]; b[6] = hi[2]; b[7] = hi[3];
                Oacc[nt] = __builtin_amdgcn_mfma_f32_16x16x32_bf16(pa, b, Oacc[nt], 0, 0, 0);
            }
        }
        // ---- epilogue: unnormalized partials ----
        float* Oz = Opart + (size_t)z * S_LEN * EMB;
        #pragma unroll
        for (int nt = 0; nt < 4; ++nt) {
            #pragma unroll
            for (int r = 0; r < 4; ++r) {
                int ri = mi * 16 + quad * 4 + r;
                Oz[(size_t)(qb + ri) * EMB + h * DH + ni * 64 + nt * 16 + l15] = Oacc[nt][r];
            }
        }
        if (ni == 0 && l15 == 0) {
            #pragma unroll
            for (int r = 0; r < 4; ++r) {
                int ri = mi * 16 + quad * 4 + r;
                msplit[(z * NHEAD + h) * S_LEN + qb + ri] = m_r[r];
                lsplit[(z * NHEAD + h) * S_LEN + qb + ri] = l_r[r];
            }
        }
    }
}

// ---------------------------------------------------------------------------
// Kernel 5: combine split-K partials + normalize + residual LayerNorm.
// ---------------------------------------------------------------------------
__global__ __launch_bounds__(256) void combine_ln_kernel(
    const float* __restrict__ Opart, const float* __restrict__ msplit,
    const float* __restrict__ lsplit, const float* __restrict__ lnw,
    float* __restrict__ out)
{
    const int s = blockIdx.x, tid = threadIdx.x;
    __shared__ float es_s[NSPLIT][NHEAD];
    __shared__ float rn_s[NHEAD];
    __shared__ float red[4];
    if (tid < NHEAD) {
        float m0 = msplit[(0 * NHEAD + tid) * S_LEN + s];
        float m1 = msplit[(1 * NHEAD + tid) * S_LEN + s];
        float m2 = msplit[(2 * NHEAD + tid) * S_LEN + s];
        float m = fmaxf(m0, fmaxf(m1, m2));
        float e0 = __expf(m0 - m), e1 = __expf(m1 - m), e2 = __expf(m2 - m);
        float l = e0 * lsplit[(0 * NHEAD + tid) * S_LEN + s]
                + e1 * lsplit[(1 * NHEAD + tid) * S_LEN + s]
                + e2 * lsplit[(2 * NHEAD + tid) * S_LEN + s];
        es_s[0][tid] = e0; es_s[1][tid] = e1; es_s[2][tid] = e2;
        rn_s[tid] = 1.f / (fmaxf(fabsf(l), __expf(-m)) + 1e-6f);
    }
    __syncthreads();
    const size_t SE = (size_t)S_LEN * EMB;
    float x[4];
    float sum = 0.f;
    #pragma unroll
    for (int i = 0; i < 4; i++) {
        int col = tid + i * 256;
        int hh = col >> 7;
        size_t off = (size_t)s * EMB + col;
        float val = es_s[0][hh] * Opart[off]
                  + es_s[1][hh] * Opart[SE + off]
                  + es_s[2][hh] * Opart[2 * SE + off];
        x[i] = val * rn_s[hh];
        sum += x[i];
    }
    for (int o = 32; o > 0; o >>= 1) sum += __shfl_down(sum, o, 64);
    if ((tid & 63) == 0) red[tid >> 6] = sum;
    __syncthreads();
    sum = red[0] + red[1] + red[2] + red[3];
    const float mu = sum * (1.f / EMB);
    float vs = 0.f;
    #pragma unroll
    for (int i = 0; i < 4; i++) { float d = x[i] - mu; vs += d * d; }
    __syncthreads();
    for (int o = 32; o > 0; o >>= 1) vs += __shfl_down(vs, o, 64);
    if ((tid & 63) == 0) red[tid >> 6] = vs;
    __syncthreads();
    vs = red[0] + red[1] + red[2] + red[3];
    const float rstd = rsqrtf(vs * (1.f / EMB) + 1e-5f);
    #pragma unroll
    for (int i = 0; i < 4; i++) {
        int c = tid + i * 256;
        out[(size_t)s * EMB + c] = (x[i] - mu) * rstd * (1.f + lnw[c]);
    }
}

// ---------------------------------------------------------------------------
extern "C" void kernel_launch(void* const* d_in, const int* in_sizes, int n_in,
                              void* d_out, int out_size, void* d_ws, size_t ws_size,
                              hipStream_t stream)
{
    const float* q   = (const float*)d_in[0];
    const float* k   = (const float*)d_in[1];
    const float* v   = (const float*)d_in[2];
    const float* Wi  = (const float*)d_in[3];
    const float* bi  = (const float*)d_in[4];
    const float* Wf  = (const float*)d_in[5];
    const float* bf  = (const float*)d_in[6];
    const float* lnw = (const float*)d_in[7];
    float* out = (float*)d_out;

    // workspace layout (floats first, then bf16 arrays, then big fp32):
    float* ws = (float*)d_ws;
    float* ig    = ws;                          // NH*S
    float* lf    = ig + NHEAD * S_LEN;          // NH*S
    float* F     = lf + NHEAD * S_LEN;          // NH*(S+1)
    float* ugw   = F + NHEAD * (S_LEN + 1);     // NH*S
    float* umaxw = ugw + NHEAD * S_LEN;         // NH*64
    float* upmaxw= umaxw + NHEAD * 64;          // NH*S
    __bf16* Qh = (__bf16*)(upmaxw + NHEAD * S_LEN);
    const size_t SEb = (size_t)S_LEN * EMB;
    __bf16* Ql  = Qh + SEb;
    __bf16* Kh  = Ql + SEb;
    __bf16* Kl  = Kh + SEb;
    __bf16* Vtg = Kl + SEb;
    float* Opart  = (float*)(Vtg + SEb);        // 3*S*EMB
    float* msplit = Opart + (size_t)NSPLIT * S_LEN * EMB;
    float* lsplit = msplit + NSPLIT * NHEAD * S_LEN;

    gates_cvt_kernel<<<S_LEN, 256, 0, stream>>>(
        q, k, v, Wi, bi, Wf, bf, Qh, Ql, Kh, Kl, ig, lf);
    transpose_v_kernel<<<dim3(S_LEN / 32, EMB / 32), 256, 0, stream>>>(v, Vtg);
    cumsum_aux_kernel<<<NHEAD, 256, 0, stream>>>(lf, ig, F, ugw, umaxw, upmaxw);
    mlstm_mfma<<<32 * NHEAD * NSPLIT, 256, 0, stream>>>(
        Qh, Ql, Kh, Kl, Vtg, ugw, umaxw, upmaxw, F, Opart, msplit, lsplit);
    combine_ln_kernel<<<S_LEN, 256, 0, stream>>>(Opart, msplit, lsplit, lnw, out);
}